// Round 2
// baseline (9539.513 us; speedup 1.0000x reference)
//
#include <hip/hip_runtime.h>

#define Nn 256
#define Tt 128
#define Dd 512
#define Hh 1024
#define G4 4096   // 4*H
#define KK 2560   // D + H + H

typedef __attribute__((ext_vector_type(8))) short s8v;
typedef __attribute__((ext_vector_type(4))) float f4v;

__device__ __forceinline__ float bf2f(ushort u) {
    union { unsigned int i; float f; } v; v.i = ((unsigned int)u) << 16; return v.f;
}
__device__ __forceinline__ ushort f2bf(float f) {   // round-to-nearest-even
    union { float f; unsigned int i; } v; v.f = f;
    unsigned int x = v.i;
    return (ushort)((x + 0x7fffu + ((x >> 16) & 1u)) >> 16);
}
__device__ __forceinline__ void split2(float f, ushort& hi, ushort& lo) {
    hi = f2bf(f);
    lo = f2bf(f - bf2f(hi));
}

// ---------------------------------------------------------------------------
// One-time: W = [Wx; Wh; Wattn] (2560 x 4096 fp32) -> Whi/Wlo[j][k] bf16
// (transposed, split into hi + residual-lo)
// ---------------------------------------------------------------------------
__global__ __launch_bounds__(256) void prep_W(
    const float* __restrict__ Wx, const float* __restrict__ Wh,
    const float* __restrict__ Wa, ushort* __restrict__ Whi,
    ushort* __restrict__ Wlo)
{
    __shared__ float tile[64 * 65];
    int kb = blockIdx.x * 64;
    int jb = blockIdx.y * 64;
    const float* src; int kofs;
    if (kb < Dd)            { src = Wx; kofs = kb; }
    else if (kb < Dd + Hh)  { src = Wh; kofs = kb - Dd; }
    else                    { src = Wa; kofs = kb - Dd - Hh; }
    int tid = threadIdx.x;
    int r = tid >> 2;            // 0..63
    int c16 = (tid & 3) * 16;    // 0,16,32,48
    const float* sp = src + (size_t)(kofs + r) * G4 + jb + c16;
    #pragma unroll
    for (int i = 0; i < 16; i++) tile[(c16 + i) * 65 + r] = sp[i];
    __syncthreads();
    ushort hi[16], lo[16];
    #pragma unroll
    for (int i = 0; i < 16; i++) split2(tile[r * 65 + c16 + i], hi[i], lo[i]);
    size_t o = (size_t)(jb + r) * KK + kb + c16;
    #pragma unroll
    for (int p = 0; p < 2; p++) {
        s8v vh, vl;
        #pragma unroll
        for (int i = 0; i < 8; i++) { vh[i] = (short)hi[p * 8 + i]; vl[i] = (short)lo[p * 8 + i]; }
        *(s8v*)&Whi[o + p * 8] = vh;
        *(s8v*)&Wlo[o + p * 8] = vl;
    }
}

// ---------------------------------------------------------------------------
// One-time: h0 = c0 = mean_l A[n][h][l]   (fp32)
// ---------------------------------------------------------------------------
__global__ __launch_bounds__(256) void init_h0(
    const float* __restrict__ A, float* __restrict__ h, float* __restrict__ c)
{
    int i = blockIdx.x * 256 + threadIdx.x;   // < N*H
    const float* ap = A + (size_t)i * 16;
    float s = 0.f;
    #pragma unroll
    for (int l = 0; l < 16; l++) s += ap[l];
    s *= (1.f / 16.f);
    h[i] = s; c[i] = s;
}

// ---------------------------------------------------------------------------
// Per step: scores[n][l] = scale * sum_h A[n][h][l]*h[n][h]; softmax over l;
// att[n][h] = sum_l A[n][h][l]*w[l]   (one block per n; all fp32)
// ---------------------------------------------------------------------------
__global__ __launch_bounds__(256) void attn_step(
    const float* __restrict__ A, const float* __restrict__ h,
    float* __restrict__ att)
{
    int n = blockIdx.x;
    int tid = threadIdx.x;
    int lane = tid & 63, wave = tid >> 6;
    __shared__ float red[4][16];
    __shared__ float wsm[16];
    float part[16];
    #pragma unroll
    for (int l = 0; l < 16; l++) part[l] = 0.f;
    const float* An = A + (size_t)n * Hh * 16;
    for (int hh = tid; hh < Hh; hh += 256) {
        float hv = h[n * Hh + hh];
        const float* ap = An + hh * 16;
        #pragma unroll
        for (int l = 0; l < 16; l++) part[l] += ap[l] * hv;
    }
    #pragma unroll
    for (int l = 0; l < 16; l++) {
        float v = part[l];
        #pragma unroll
        for (int off = 32; off > 0; off >>= 1) v += __shfl_down(v, off);
        if (lane == 0) red[wave][l] = v;
    }
    __syncthreads();
    if (tid == 0) {
        float sc[16]; float mx = -3.4e38f;
        #pragma unroll
        for (int l = 0; l < 16; l++) {
            sc[l] = (red[0][l] + red[1][l] + red[2][l] + red[3][l]) * 0.03125f;
            mx = fmaxf(mx, sc[l]);
        }
        float sum = 0.f;
        #pragma unroll
        for (int l = 0; l < 16; l++) { sc[l] = expf(sc[l] - mx); sum += sc[l]; }
        float inv = 1.f / sum;
        #pragma unroll
        for (int l = 0; l < 16; l++) wsm[l] = sc[l] * inv;
    }
    __syncthreads();
    for (int hh = tid; hh < Hh; hh += 256) {
        const float* ap = An + hh * 16;
        float s = 0.f;
        #pragma unroll
        for (int l = 0; l < 16; l++) s += ap[l] * wsm[l];
        att[n * Hh + hh] = s;
    }
}

// ---------------------------------------------------------------------------
// Per step: gates[n][j] = b[j] + [x_t | h | att](n,:) @ W(:,j)  (split-bf16)
// M=256, N=4096, K=2560.  64x64 tile, BK=64, 4 waves (each 16 rows x 64 cols).
// C ~= Ahi*Bhi + Ahi*Blo + Alo*Bhi  (fp32 accumulate)
// MFMA 16x16x32 bf16: A[m=lane&15][k=quad*8+j]; B[k=quad*8+j][n=lane&15];
// C/D: col=lane&15, row=quad*4+reg.
// ---------------------------------------------------------------------------
__global__ __launch_bounds__(256) void gemm_gates(
    const float* __restrict__ x, const float* __restrict__ h,
    const float* __restrict__ att, const ushort* __restrict__ Whi,
    const ushort* __restrict__ Wlo, const float* __restrict__ bias,
    float* __restrict__ gates, int t)
{
    __shared__ ushort Ahi[64 * 72], Alo[64 * 72];
    __shared__ ushort Bhi[64 * 72], Blo[64 * 72];
    int j0 = blockIdx.x * 64;
    int n0 = blockIdx.y * 64;
    int tid = threadIdx.x;
    int lane = tid & 63, wave = tid >> 6;
    int l15 = lane & 15, quad = lane >> 4;
    f4v acc[4];
    #pragma unroll
    for (int s = 0; s < 4; s++) acc[s] = (f4v){0.f, 0.f, 0.f, 0.f};

    int r = tid >> 2;            // 0..63
    int c16 = (tid & 3) * 16;    // 0,16,32,48

    for (int kb = 0; kb < KK; kb += 64) {
        const float* src; int rstride, kofs;
        if (kb < Dd)           { src = x + (size_t)t * Dd; rstride = Tt * Dd; kofs = kb; }
        else if (kb < Dd + Hh) { src = h;   rstride = Hh; kofs = kb - Dd; }
        else                   { src = att; rstride = Hh; kofs = kb - Dd - Hh; }
        __syncthreads();
        // A tile: 16 fp32 per thread, split into hi/lo bf16
        {
            const float* ap = src + (size_t)(n0 + r) * rstride + kofs + c16;
            ushort hi[16], lo[16];
            #pragma unroll
            for (int i = 0; i < 16; i++) split2(ap[i], hi[i], lo[i]);
            #pragma unroll
            for (int p = 0; p < 2; p++) {
                s8v vh, vl;
                #pragma unroll
                for (int i = 0; i < 8; i++) { vh[i] = (short)hi[p * 8 + i]; vl[i] = (short)lo[p * 8 + i]; }
                *(s8v*)&Ahi[r * 72 + c16 + p * 8] = vh;
                *(s8v*)&Alo[r * 72 + c16 + p * 8] = vl;
            }
        }
        // B tile: preformed bf16 hi/lo, straight copies
        {
            size_t o = (size_t)(j0 + r) * KK + kb + c16;
            #pragma unroll
            for (int p = 0; p < 2; p++) {
                *(s8v*)&Bhi[r * 72 + c16 + p * 8] = *(const s8v*)&Whi[o + p * 8];
                *(s8v*)&Blo[r * 72 + c16 + p * 8] = *(const s8v*)&Wlo[o + p * 8];
            }
        }
        __syncthreads();
        #pragma unroll
        for (int ks = 0; ks < 2; ks++) {
            s8v ah = *(const s8v*)&Ahi[(wave * 16 + l15) * 72 + ks * 32 + quad * 8];
            s8v al = *(const s8v*)&Alo[(wave * 16 + l15) * 72 + ks * 32 + quad * 8];
            #pragma unroll
            for (int s = 0; s < 4; s++) {
                s8v bh = *(const s8v*)&Bhi[(s * 16 + l15) * 72 + ks * 32 + quad * 8];
                s8v bl = *(const s8v*)&Blo[(s * 16 + l15) * 72 + ks * 32 + quad * 8];
                acc[s] = __builtin_amdgcn_mfma_f32_16x16x32_bf16(ah, bh, acc[s], 0, 0, 0);
                acc[s] = __builtin_amdgcn_mfma_f32_16x16x32_bf16(ah, bl, acc[s], 0, 0, 0);
                acc[s] = __builtin_amdgcn_mfma_f32_16x16x32_bf16(al, bh, acc[s], 0, 0, 0);
            }
        }
    }
    #pragma unroll
    for (int s = 0; s < 4; s++) {
        int j = j0 + s * 16 + l15;
        float bv = bias[j];
        #pragma unroll
        for (int rr = 0; rr < 4; rr++) {
            int row = n0 + wave * 16 + quad * 4 + rr;
            gates[(size_t)row * G4 + j] = acc[s][rr] + bv;
        }
    }
}

// ---------------------------------------------------------------------------
// Per step: LSTM pointwise update; writes h,c (fp32) and out[n][t][:] (fp32)
// ---------------------------------------------------------------------------
__global__ __launch_bounds__(256) void lstm_update(
    const float* __restrict__ gates, float* __restrict__ c, float* __restrict__ h,
    float* __restrict__ out, int t)
{
    int i = blockIdx.x * 256 + threadIdx.x;   // < N*H
    int n = i >> 10, j = i & 1023;
    const float* g = gates + (size_t)n * G4;
    float gi = g[j], gf = g[Hh + j], go = g[2 * Hh + j], gg = g[3 * Hh + j];
    float si = 1.f / (1.f + expf(-gi));
    float sf = 1.f / (1.f + expf(-gf));
    float so = 1.f / (1.f + expf(-go));
    float tg = tanhf(gg);
    float cn = sf * c[i] + si * tg;
    float hn = so * tanhf(cn);
    c[i] = cn; h[i] = hn;
    out[((size_t)n * Tt + t) * Hh + j] = hn;
}

// ---------------------------------------------------------------------------
extern "C" void kernel_launch(void* const* d_in, const int* in_sizes, int n_in,
                              void* d_out, int out_size, void* d_ws, size_t ws_size,
                              hipStream_t stream)
{
    const float* x  = (const float*)d_in[0];
    const float* A  = (const float*)d_in[1];
    const float* Wx = (const float*)d_in[2];
    const float* Wh = (const float*)d_in[3];
    const float* Wa = (const float*)d_in[4];
    const float* b  = (const float*)d_in[5];
    float* out = (float*)d_out;

    // workspace layout (~49 MB)
    char* p = (char*)d_ws;
    ushort* Whi  = (ushort*)p;  p += (size_t)G4 * KK * 2;   // 20.97 MB
    ushort* Wlo  = (ushort*)p;  p += (size_t)G4 * KK * 2;   // 20.97 MB
    float*  h    = (float*)p;   p += (size_t)Nn * Hh * 4;   // 1 MB
    float*  c    = (float*)p;   p += (size_t)Nn * Hh * 4;   // 1 MB
    float*  att  = (float*)p;   p += (size_t)Nn * Hh * 4;   // 1 MB
    float*  gate = (float*)p;   p += (size_t)Nn * G4 * 4;   // 4 MB

    prep_W<<<dim3(KK / 64, G4 / 64), 256, 0, stream>>>(Wx, Wh, Wa, Whi, Wlo);
    init_h0<<<(Nn * Hh) / 256, 256, 0, stream>>>(A, h, c);
    for (int t = 0; t < Tt; t++) {
        attn_step<<<Nn, 256, 0, stream>>>(A, h, att);
        gemm_gates<<<dim3(G4 / 64, Nn / 64), 256, 0, stream>>>(x, h, att, Whi, Wlo, b, gate, t);
        lstm_update<<<(Nn * Hh) / 256, 256, 0, stream>>>(gate, c, h, out, t);
    }
}

// Round 3
// 6327.071 us; speedup vs baseline: 1.5077x; 1.5077x over previous
//
#include <hip/hip_runtime.h>

#define Nn 256
#define Tt 128
#define Dd 512
#define Hh 1024
#define G4 4096   // 4*H
#define KK 2560   // D + H + H
#define KHALF 1280

typedef __attribute__((ext_vector_type(8))) short s8v;
typedef __attribute__((ext_vector_type(4))) float f4v;

__device__ __forceinline__ float bf2f(ushort u) {
    union { unsigned int i; float f; } v; v.i = ((unsigned int)u) << 16; return v.f;
}
__device__ __forceinline__ ushort f2bf(float f) {   // round-to-nearest-even
    union { float f; unsigned int i; } v; v.f = f;
    unsigned int x = v.i;
    return (ushort)((x + 0x7fffu + ((x >> 16) & 1u)) >> 16);
}
__device__ __forceinline__ void split2(float f, ushort& hi, ushort& lo) {
    hi = f2bf(f);
    lo = f2bf(f - bf2f(hi));
}

// ---------------------------------------------------------------------------
// One-time: W = [Wx; Wh; Wattn] (2560 x 4096 fp32) -> Whi/Wlo[j][k] bf16
// ---------------------------------------------------------------------------
__global__ __launch_bounds__(256) void prep_W(
    const float* __restrict__ Wx, const float* __restrict__ Wh,
    const float* __restrict__ Wa, ushort* __restrict__ Whi,
    ushort* __restrict__ Wlo)
{
    __shared__ float tile[64 * 65];
    int kb = blockIdx.x * 64;
    int jb = blockIdx.y * 64;
    const float* src; int kofs;
    if (kb < Dd)            { src = Wx; kofs = kb; }
    else if (kb < Dd + Hh)  { src = Wh; kofs = kb - Dd; }
    else                    { src = Wa; kofs = kb - Dd - Hh; }
    int tid = threadIdx.x;
    int r = tid >> 2;            // 0..63
    int c16 = (tid & 3) * 16;    // 0,16,32,48
    const float* sp = src + (size_t)(kofs + r) * G4 + jb + c16;
    #pragma unroll
    for (int i = 0; i < 16; i++) tile[(c16 + i) * 65 + r] = sp[i];
    __syncthreads();
    ushort hi[16], lo[16];
    #pragma unroll
    for (int i = 0; i < 16; i++) split2(tile[r * 65 + c16 + i], hi[i], lo[i]);
    size_t o = (size_t)(jb + r) * KK + kb + c16;
    #pragma unroll
    for (int p = 0; p < 2; p++) {
        s8v vh, vl;
        #pragma unroll
        for (int i = 0; i < 8; i++) { vh[i] = (short)hi[p * 8 + i]; vl[i] = (short)lo[p * 8 + i]; }
        *(s8v*)&Whi[o + p * 8] = vh;
        *(s8v*)&Wlo[o + p * 8] = vl;
    }
}

// ---------------------------------------------------------------------------
// One-time: h0 = c0 = mean_l A[n][h][l];  also h0 split hi/lo
// ---------------------------------------------------------------------------
__global__ __launch_bounds__(256) void init_h0(
    const float* __restrict__ A, float* __restrict__ h, float* __restrict__ c,
    ushort* __restrict__ hhi, ushort* __restrict__ hlo)
{
    int i = blockIdx.x * 256 + threadIdx.x;   // < N*H
    const float* ap = A + (size_t)i * 16;
    float s = 0.f;
    #pragma unroll
    for (int l = 0; l < 16; l++) s += ap[l];
    s *= (1.f / 16.f);
    h[i] = s; c[i] = s;
    ushort hi, lo; split2(s, hi, lo);
    hhi[i] = hi; hlo[i] = lo;
}

// ---------------------------------------------------------------------------
// Per step: softmax attention over 16 locations; one block per n.
// A cached in registers across both passes. Writes attn split hi/lo.
// ---------------------------------------------------------------------------
__global__ __launch_bounds__(256) void attn_step(
    const float* __restrict__ A, const float* __restrict__ h,
    ushort* __restrict__ athi, ushort* __restrict__ atlo)
{
    int n = blockIdx.x;
    int tid = threadIdx.x;
    int lane = tid & 63, wave = tid >> 6;
    __shared__ float red[4][16];
    __shared__ float wsm[16];
    const float* An = A + (size_t)n * Hh * 16;
    float areg[4][16];
    float hreg[4];
    #pragma unroll
    for (int rr = 0; rr < 4; rr++) {
        int hh = tid + rr * 256;
        const f4v* ap = (const f4v*)(An + (size_t)hh * 16);
        #pragma unroll
        for (int q = 0; q < 4; q++) {
            f4v v = ap[q];
            areg[rr][q * 4 + 0] = v[0]; areg[rr][q * 4 + 1] = v[1];
            areg[rr][q * 4 + 2] = v[2]; areg[rr][q * 4 + 3] = v[3];
        }
        hreg[rr] = h[n * Hh + hh];
    }
    float part[16];
    #pragma unroll
    for (int l = 0; l < 16; l++) part[l] = 0.f;
    #pragma unroll
    for (int rr = 0; rr < 4; rr++)
        #pragma unroll
        for (int l = 0; l < 16; l++) part[l] += areg[rr][l] * hreg[rr];
    #pragma unroll
    for (int l = 0; l < 16; l++) {
        float v = part[l];
        #pragma unroll
        for (int off = 32; off > 0; off >>= 1) v += __shfl_down(v, off);
        if (lane == 0) red[wave][l] = v;
    }
    __syncthreads();
    if (tid == 0) {
        float sc[16]; float mx = -3.4e38f;
        #pragma unroll
        for (int l = 0; l < 16; l++) {
            sc[l] = (red[0][l] + red[1][l] + red[2][l] + red[3][l]) * 0.03125f;
            mx = fmaxf(mx, sc[l]);
        }
        float sum = 0.f;
        #pragma unroll
        for (int l = 0; l < 16; l++) { sc[l] = expf(sc[l] - mx); sum += sc[l]; }
        float inv = 1.f / sum;
        #pragma unroll
        for (int l = 0; l < 16; l++) wsm[l] = sc[l] * inv;
    }
    __syncthreads();
    float w[16];
    #pragma unroll
    for (int l = 0; l < 16; l++) w[l] = wsm[l];
    #pragma unroll
    for (int rr = 0; rr < 4; rr++) {
        int hh = tid + rr * 256;
        float s = 0.f;
        #pragma unroll
        for (int l = 0; l < 16; l++) s += areg[rr][l] * w[l];
        ushort hi, lo; split2(s, hi, lo);
        athi[n * Hh + hh] = hi; atlo[n * Hh + hh] = lo;
    }
}

// ---------------------------------------------------------------------------
// Per step, K-split halves (blockIdx.z): partial gates, no bias.
// grid (64 j, 4 n, 2 k-halves), 256 threads. Pre-split activations except x.
// ---------------------------------------------------------------------------
__global__ __launch_bounds__(256) void gemm_half(
    const float* __restrict__ x,
    const ushort* __restrict__ hhi, const ushort* __restrict__ hlo,
    const ushort* __restrict__ athi, const ushort* __restrict__ atlo,
    const ushort* __restrict__ Whi, const ushort* __restrict__ Wlo,
    float* __restrict__ g0, float* __restrict__ g1, int t)
{
    __shared__ ushort Ahi[64 * 72], Alo[64 * 72];
    __shared__ ushort Bhi[64 * 72], Blo[64 * 72];
    int j0 = blockIdx.x * 64;
    int n0 = blockIdx.y * 64;
    int kb0 = blockIdx.z * KHALF;
    float* gout = blockIdx.z ? g1 : g0;
    int tid = threadIdx.x;
    int lane = tid & 63, wave = tid >> 6;
    int l15 = lane & 15, quad = lane >> 4;
    f4v acc[4];
    #pragma unroll
    for (int s = 0; s < 4; s++) acc[s] = (f4v){0.f, 0.f, 0.f, 0.f};

    int rs = tid >> 3;            // 0..31 (second pass +32)
    int cs = (tid & 7) * 8;       // k-chunk offset

    for (int kb = kb0; kb < kb0 + KHALF; kb += 64) {
        __syncthreads();
        if (kb < Dd) {
            const float* xs = x + (size_t)t * Dd + kb + cs;
            #pragma unroll
            for (int p = 0; p < 2; p++) {
                int r = rs + 32 * p;
                const float* ap = xs + (size_t)(n0 + r) * (Tt * Dd);
                s8v vh, vl;
                #pragma unroll
                for (int i = 0; i < 8; i++) {
                    ushort hi_, lo_; split2(ap[i], hi_, lo_);
                    vh[i] = (short)hi_; vl[i] = (short)lo_;
                }
                *(s8v*)&Ahi[r * 72 + cs] = vh;
                *(s8v*)&Alo[r * 72 + cs] = vl;
            }
        } else {
            const ushort *sh, *sl; int kofs;
            if (kb < Dd + Hh) { sh = hhi; sl = hlo; kofs = kb - Dd; }
            else              { sh = athi; sl = atlo; kofs = kb - Dd - Hh; }
            #pragma unroll
            for (int p = 0; p < 2; p++) {
                int r = rs + 32 * p;
                size_t o = (size_t)(n0 + r) * Hh + kofs + cs;
                *(s8v*)&Ahi[r * 72 + cs] = *(const s8v*)&sh[o];
                *(s8v*)&Alo[r * 72 + cs] = *(const s8v*)&sl[o];
            }
        }
        #pragma unroll
        for (int p = 0; p < 2; p++) {
            int r = rs + 32 * p;
            size_t o = (size_t)(j0 + r) * KK + kb + cs;
            *(s8v*)&Bhi[r * 72 + cs] = *(const s8v*)&Whi[o];
            *(s8v*)&Blo[r * 72 + cs] = *(const s8v*)&Wlo[o];
        }
        __syncthreads();
        #pragma unroll
        for (int ks = 0; ks < 2; ks++) {
            s8v ah = *(const s8v*)&Ahi[(wave * 16 + l15) * 72 + ks * 32 + quad * 8];
            s8v al = *(const s8v*)&Alo[(wave * 16 + l15) * 72 + ks * 32 + quad * 8];
            #pragma unroll
            for (int s = 0; s < 4; s++) {
                s8v bh = *(const s8v*)&Bhi[(s * 16 + l15) * 72 + ks * 32 + quad * 8];
                s8v bl = *(const s8v*)&Blo[(s * 16 + l15) * 72 + ks * 32 + quad * 8];
                acc[s] = __builtin_amdgcn_mfma_f32_16x16x32_bf16(ah, bh, acc[s], 0, 0, 0);
                acc[s] = __builtin_amdgcn_mfma_f32_16x16x32_bf16(ah, bl, acc[s], 0, 0, 0);
                acc[s] = __builtin_amdgcn_mfma_f32_16x16x32_bf16(al, bh, acc[s], 0, 0, 0);
            }
        }
    }
    #pragma unroll
    for (int s = 0; s < 4; s++) {
        int j = j0 + s * 16 + l15;
        #pragma unroll
        for (int rr = 0; rr < 4; rr++) {
            int row = n0 + wave * 16 + quad * 4 + rr;
            gout[(size_t)row * G4 + j] = acc[s][rr];
        }
    }
}

// ---------------------------------------------------------------------------
// Per step: LSTM pointwise; sums the two K-halves + bias; writes c, h (fp32),
// h split hi/lo, out[n][t][:]
// ---------------------------------------------------------------------------
__global__ __launch_bounds__(256) void lstm_update(
    const float* __restrict__ g0, const float* __restrict__ g1,
    const float* __restrict__ bias,
    float* __restrict__ c, float* __restrict__ h,
    ushort* __restrict__ hhi, ushort* __restrict__ hlo,
    float* __restrict__ out, int t)
{
    int i = blockIdx.x * 256 + threadIdx.x;   // < N*H
    int n = i >> 10, j = i & 1023;
    size_t base = (size_t)n * G4;
    float gi = g0[base + j]          + g1[base + j]          + bias[j];
    float gf = g0[base + Hh + j]     + g1[base + Hh + j]     + bias[Hh + j];
    float go = g0[base + 2 * Hh + j] + g1[base + 2 * Hh + j] + bias[2 * Hh + j];
    float gg = g0[base + 3 * Hh + j] + g1[base + 3 * Hh + j] + bias[3 * Hh + j];
    float si = 1.f / (1.f + expf(-gi));
    float sf = 1.f / (1.f + expf(-gf));
    float so = 1.f / (1.f + expf(-go));
    float tg = tanhf(gg);
    float cn = sf * c[i] + si * tg;
    float hn = so * tanhf(cn);
    c[i] = cn; h[i] = hn;
    ushort hi, lo; split2(hn, hi, lo);
    hhi[i] = hi; hlo[i] = lo;
    out[((size_t)n * Tt + t) * Hh + j] = hn;
}

// ---------------------------------------------------------------------------
extern "C" void kernel_launch(void* const* d_in, const int* in_sizes, int n_in,
                              void* d_out, int out_size, void* d_ws, size_t ws_size,
                              hipStream_t stream)
{
    const float* x  = (const float*)d_in[0];
    const float* A  = (const float*)d_in[1];
    const float* Wx = (const float*)d_in[2];
    const float* Wh = (const float*)d_in[3];
    const float* Wa = (const float*)d_in[4];
    const float* b  = (const float*)d_in[5];
    float* out = (float*)d_out;

    // workspace layout (~54 MB)
    char* p = (char*)d_ws;
    ushort* Whi  = (ushort*)p;  p += (size_t)G4 * KK * 2;   // 20.97 MB
    ushort* Wlo  = (ushort*)p;  p += (size_t)G4 * KK * 2;   // 20.97 MB
    float*  h    = (float*)p;   p += (size_t)Nn * Hh * 4;   // 1 MB
    float*  c    = (float*)p;   p += (size_t)Nn * Hh * 4;   // 1 MB
    float*  g0   = (float*)p;   p += (size_t)Nn * G4 * 4;   // 4 MB
    float*  g1   = (float*)p;   p += (size_t)Nn * G4 * 4;   // 4 MB
    ushort* hhi  = (ushort*)p;  p += (size_t)Nn * Hh * 2;   // 0.5 MB
    ushort* hlo  = (ushort*)p;  p += (size_t)Nn * Hh * 2;   // 0.5 MB
    ushort* athi = (ushort*)p;  p += (size_t)Nn * Hh * 2;   // 0.5 MB
    ushort* atlo = (ushort*)p;  p += (size_t)Nn * Hh * 2;   // 0.5 MB

    prep_W<<<dim3(KK / 64, G4 / 64), 256, 0, stream>>>(Wx, Wh, Wa, Whi, Wlo);
    init_h0<<<(Nn * Hh) / 256, 256, 0, stream>>>(A, h, c, hhi, hlo);
    for (int t = 0; t < Tt; t++) {
        attn_step<<<Nn, 256, 0, stream>>>(A, h, athi, atlo);
        gemm_half<<<dim3(G4 / 64, Nn / 64, 2), 256, 0, stream>>>(
            x, hhi, hlo, athi, atlo, Whi, Wlo, g0, g1, t);
        lstm_update<<<(Nn * Hh) / 256, 256, 0, stream>>>(
            g0, g1, b, c, h, hhi, hlo, out, t);
    }
}